// Round 5
// baseline (340.619 us; speedup 1.0000x reference)
//
#include <hip/hip_runtime.h>

// ---------------------------------------------------------------------------
// PositionEncoder: per token (B*T = 262144), output 272 f32:
//   x[0:6] | emb[idx1] (128) | x[6:10] | emb[idx2] (128) | x[10:16]
//
// R9 = MEASUREMENT PROBE (intentionally ~2x slower than R8).
//  R0..R8 history: five structurally different kernels (LDS-tile/direct/
//  template x plain/nt stores, 4-8 blk/CU, 1-3 barriers) all pinned at
//  115-125 us kernel-resid vs a ~50 us no-RFO floor. Our kernel has NEVER
//  appeared in the top-5 counter table (harness poison fills ~180 us hide
//  it), so FETCH/WRITE for our store stream were never observed.
//  This probe stores the output TWICE (identical values; memory-clobber
//  between passes prevents dead-store elim) to push the kernel above the
//  fills into the top-5 and directly read its FETCH_SIZE / WRITE_SIZE:
//    FETCH >> 30 MB  => write-allocate (RFO) real => R8 was at the floor.
//    FETCH ~  20 MB  => no RFO => single-pass floor is ~55 us, keep digging.
//    WRITE ~ 285 MB  => L2 merged the double-write => writeback-limited.
// ---------------------------------------------------------------------------

#define TOK 64          // tokens per block
#define THREADS 256

typedef float vfloat4 __attribute__((ext_vector_type(4)));  // native vector

constexpr float kNX[26] = {
    0.5454545454545454f, 0.6022727272727273f, 0.5454545454545454f,
    0.6022727272727273f, 0.4772727272727273f, 0.42045454545454547f,
    0.42045454545454547f, 0.4772727272727273f, 0.32954545454545453f,
    0.42045454545454547f, 0.4772727272727273f, 0.4772727272727273f,
    0.42045454545454547f, 0.32954545454545453f, 0.5727272727272728f,
    0.7613636363636364f, 0.8181818181818182f, 0.8181818181818182f,
    0.7613636363636364f, 0.7909090909090909f, 0.9431818181818182f,
    1.0f, 1.0f, 0.9431818181818182f, 0.9727272727272728f, 0.9727272727272728f};
constexpr float kNY[26] = {
    0.76f, 0.76f, 0.86f, 0.86f, 0.76f, 0.76f, 0.86f, 0.86f, 0.808f,
    0.48f, 0.48f, 0.38f, 0.38f, 0.428f, 0.62f, 0.76f, 0.76f, 0.86f,
    0.86f, 0.62f, 0.76f, 0.76f, 0.86f, 0.86f, 0.62f, 1.0f};

__device__ __forceinline__ int point_index(float px, float py) {
#pragma clang fp contract(off)
    int idx = 0;
#pragma unroll
    for (int n = 25; n >= 0; --n) {
        float tx = 0.01f + 1.0e-5f * kNX[n];
        float ty = 0.01f + 1.0e-5f * kNY[n];
        bool c = (fabsf(px - kNX[n]) <= tx) && (fabsf(py - kNY[n]) <= ty);
        if (c) idx = n + 1;
    }
    return idx;
}

__global__ __launch_bounds__(THREADS) void pos_enc_kernel(
    const float* __restrict__ x, const float* __restrict__ emb,
    float* __restrict__ out, int n_tokens) {
    __shared__ float xs[TOK * 16];      // 4 KB   staged x tile
    __shared__ float semb[27 * 128];    // 13.5 KB emb rows 0..26 (reachable set)
    __shared__ int   sidx[2 * TOK];     // 0.5 KB node indices

    const int tid  = threadIdx.x;
    const int tok0 = blockIdx.x * TOK;
    const int ntok = min(TOK, n_tokens - tok0);

    // ---- stage emb rows 0..26: 864 float4, coalesced, L2-hot after block 0
    for (int i = tid; i < 27 * 32; i += THREADS)
        ((vfloat4*)semb)[i] = ((const vfloat4*)emb)[i];

    // ---- stage x tile (1 float4/thread) + node indices from the staging reg
    if (tid < ntok * 4) {
        vfloat4 v = ((const vfloat4*)x)[(long long)tok0 * 4 + tid];
        ((vfloat4*)xs)[tid] = v;
        int q = tid & 3, t = tid >> 2;
        if (q == 1) sidx[t]       = point_index(v.x, v.y);
        if (q == 2) sidx[TOK + t] = point_index(v.x, v.y);
    }
    __syncthreads();   // the only barrier

    // Half h (float2 units, 0..135):
    //   h<3: x[2h..]  h<67: e1[2h-6..]  h<69: x[2h-128..]
    //   h<133: e2[2h-138..]  else x[2h-256..]     (verified: absmax 0)
    const float2* xs2 = (const float2*)xs;
    const float2* se2 = (const float2*)semb;
    const long long out4 = (long long)tok0 * 68;

    // exact for l < ~1M: floor(l*61681 / 2^22) == floor(l/68)
#define BODY(lv)                                                           \
    {                                                                      \
        const int l_ = (lv);                                               \
        int t  = (int)(((unsigned)l_ * 61681u) >> 22);                     \
        int j  = l_ - t * 68;                                              \
        int i1 = sidx[t];                                                  \
        int i2 = sidx[TOK + t];                                            \
        int tb = t * 8;                                                    \
        int h0 = 2 * j;                                                    \
        const float2* p0 = (h0 < 3)   ? xs2 + tb + h0                      \
                         : (h0 < 67)  ? se2 + i1 * 64 + (h0 - 3)           \
                         : (h0 < 69)  ? xs2 + tb + (h0 - 64)               \
                         : (h0 < 133) ? se2 + i2 * 64 + (h0 - 69)          \
                         :              xs2 + tb + (h0 - 128);             \
        int h1 = h0 + 1;                                                   \
        const float2* p1 = (h1 < 3)   ? xs2 + tb + h1                      \
                         : (h1 < 67)  ? se2 + i1 * 64 + (h1 - 3)           \
                         : (h1 < 69)  ? xs2 + tb + (h1 - 64)               \
                         : (h1 < 133) ? se2 + i2 * 64 + (h1 - 69)          \
                         :              xs2 + tb + (h1 - 128);             \
        float2 a = *p0, b = *p1;                                           \
        vfloat4 v; v.x = a.x; v.y = a.y; v.z = b.x; v.w = b.y;             \
        ((vfloat4*)out)[out4 + l_] = v;   /* plain store */                \
    }

    // ---- PROBE: store the whole output twice. Pass values are identical,
    // so the final memory image is unchanged (correctness preserved). The
    // memory clobber keeps pass-1 stores live (no dead-store elimination).
    for (int pass = 0; pass < 2; ++pass) {
        if (ntok == TOK) {
#pragma unroll 4
            for (int k = 0; k < 17; ++k) BODY(tid + (k << 8));
        } else {
            const int nvec = ntok * 68;
            for (int l = tid; l < nvec; l += THREADS) BODY(l);
        }
        asm volatile("" ::: "memory");
    }
#undef BODY
}

extern "C" void kernel_launch(void* const* d_in, const int* in_sizes, int n_in,
                              void* d_out, int out_size, void* d_ws, size_t ws_size,
                              hipStream_t stream) {
    const float* x   = (const float*)d_in[0];   // [B, T, 16] f32
    const float* emb = (const float*)d_in[1];   // [100, 128] f32
    float* out = (float*)d_out;                 // [B, T, 272] f32

    int n_tokens = in_sizes[0] / 16;            // 262144
    int nblocks  = (n_tokens + TOK - 1) / TOK;  // 4096

    pos_enc_kernel<<<nblocks, THREADS, 0, stream>>>(x, emb, out, n_tokens);
}